// Round 1
// baseline (331.646 us; speedup 1.0000x reference)
//
#include <hip/hip_runtime.h>
#include <stdint.h>

#define NB 118
#define MSZ (118*118)
#define EFT_S 136   // fp16 elems per LDS row (272 B = 17*16B -> aligned b128, <=2-way banks)

typedef _Float16 f16x8 __attribute__((ext_vector_type(8)));
typedef float f32x4 __attribute__((ext_vector_type(4)));

__device__ __forceinline__ f32x4 mfma16(f16x8 a, f16x8 b, f32x4 c) {
    return __builtin_amdgcn_mfma_f32_16x16x32_f16(a, b, c, 0, 0, 0);
}

// Pre-pack W1/W2 [320][64] f32 -> fp16 in MFMA B-fragment order:
// frag (t,c): lane l, j -> W[t*32 + (l>>4)*8 + j][c*16 + (l&15)]
__global__ void prep_w(const float* __restrict__ W1, const float* __restrict__ W2,
                       _Float16* __restrict__ WP)
{
    int g = blockIdx.x * 256 + threadIdx.x;
    if (g >= 5120) return;
    int wsel = g / 2560;
    int r = g % 2560;
    int t = r >> 8;
    int c = (r >> 6) & 3;
    int l = r & 63;
    const float* W = wsel ? W2 : W1;
    _Float16* dst = WP + wsel * 20480 + r * 8;
#pragma unroll
    for (int j = 0; j < 8; j++) {
        int kk = t * 32 + (l >> 4) * 8 + j;
        int col = c * 16 + (l & 15);
        dst[j] = (_Float16)W[kk * 64 + col];
    }
}

// Stage-1 matmul: acc[rf][c] += M[tile] @ EF  (A from global f32->fp16, B from LDS EFt)
__device__ __forceinline__ void stage1(const float* __restrict__ M,
                                       const _Float16* EFt_, int w, int lane,
                                       f32x4 (&acc)[2][8])
{
    const int l15 = lane & 15, lhi = lane >> 4;
#pragma unroll
    for (int t = 0; t < 4; t++) {
        f16x8 afr[2];
#pragma unroll
        for (int rf = 0; rf < 2; rf++) {
            int row = w * 32 + rf * 16 + l15;
            if (row > 117) row = 117;           // clamp pad rows (outputs discarded)
            int kb = t * 32 + lhi * 8;
            const float* p = M + row * NB + kb;
            float vv[8];
            if (t < 3) {
#pragma unroll
                for (int pr = 0; pr < 4; pr++) {
                    float2 q = *(const float2*)(p + 2 * pr);
                    vv[2 * pr] = q.x; vv[2 * pr + 1] = q.y;
                }
            } else {                            // K tail: cols >=118 are zero
#pragma unroll
                for (int pr = 0; pr < 4; pr++) {
                    int k0 = kb + 2 * pr;
                    if (k0 <= 116) {
                        float2 q = *(const float2*)(p + 2 * pr);
                        vv[2 * pr] = q.x; vv[2 * pr + 1] = q.y;
                    } else { vv[2 * pr] = 0.f; vv[2 * pr + 1] = 0.f; }
                }
            }
            f16x8 uu;
#pragma unroll
            for (int j = 0; j < 8; j++) uu[j] = (_Float16)vv[j];
            afr[rf] = uu;
        }
#pragma unroll
        for (int c = 0; c < 8; c++) {
            f16x8 bfr = *(const f16x8*)&EFt_[(c * 16 + l15) * EFT_S + t * 32 + lhi * 8];
#pragma unroll
            for (int rf = 0; rf < 2; rf++) acc[rf][c] = mfma16(afr[rf], bfr, acc[rf][c]);
        }
    }
}

// Scale + fp16-pack register tile (C/D layout) into RT [row][128]
__device__ __forceinline__ void writeRT(_Float16* RT_, const f32x4 (&src)[2][8],
                                        float sE, float sF, int w, int lane)
{
    const int l15 = lane & 15, lhi = lane >> 4;
#pragma unroll
    for (int rf = 0; rf < 2; rf++)
#pragma unroll
        for (int c = 0; c < 4; c++)
#pragma unroll
            for (int r = 0; r < 4; r++) {
                int row = w * 32 + rf * 16 + lhi * 4 + r;
                RT_[row * EFT_S + c * 16 + l15] = (_Float16)(src[rf][c][r] * sE);
                RT_[row * EFT_S + 64 + c * 16 + l15] = (_Float16)(src[rf][c + 4][r] * sF);
            }
}

// Stage-2 round j: VE += RT[:,0:64] @ W1[64j:64j+64,:], VF += RT[:,64:128] @ W2[...]
__device__ __forceinline__ void s2round(const _Float16* RT_,
                                        const _Float16* __restrict__ W1P,
                                        const _Float16* __restrict__ W2P,
                                        int j, int w, int lane,
                                        f32x4 (&VE)[2][4], f32x4 (&VF)[2][4])
{
    const int l15 = lane & 15, lhi = lane >> 4;
#pragma unroll
    for (int th = 0; th < 2; th++) {
        int t = 2 * j + th;
        f16x8 ae[2], af[2];
#pragma unroll
        for (int rf = 0; rf < 2; rf++) {
            int row = w * 32 + rf * 16 + l15;
            int kk = th * 32 + lhi * 8;
            ae[rf] = *(const f16x8*)&RT_[row * EFT_S + kk];
            af[rf] = *(const f16x8*)&RT_[row * EFT_S + 64 + kk];
        }
#pragma unroll
        for (int c = 0; c < 4; c++) {
            f16x8 bw1 = *(const f16x8*)&W1P[((t * 4 + c) * 64 + lane) * 8];
            f16x8 bw2 = *(const f16x8*)&W2P[((t * 4 + c) * 64 + lane) * 8];
#pragma unroll
            for (int rf = 0; rf < 2; rf++) {
                VE[rf][c] = mfma16(ae[rf], bw1, VE[rf][c]);
                VF[rf][c] = mfma16(af[rf], bw2, VF[rf][c]);
            }
        }
    }
}

__global__ __launch_bounds__(256, 2) void gcn_main(
    const float* __restrict__ E, const float* __restrict__ F,
    const float* __restrict__ K1, const float* __restrict__ K2,
    const float* __restrict__ Gn, const float* __restrict__ Bn,
    const float* __restrict__ Gdg, const float* __restrict__ Bdg,
    const float* __restrict__ Pdg, const float* __restrict__ Qdg,
    const float* __restrict__ b1, const float* __restrict__ b2,
    const float* __restrict__ wae, const float* __restrict__ bae,
    const float* __restrict__ waf, const float* __restrict__ baf,
    const _Float16* __restrict__ W1P, const _Float16* __restrict__ W2P,
    float* __restrict__ outE, float* __restrict__ outF)
{
    __shared__ __align__(16) _Float16 EFt[128 * EFT_S];   // [dim 0..127][node], e rows 0-63, f rows 64-127
    __shared__ __align__(16) _Float16 RT[128 * EFT_S];    // stage-2 roundtrip [node][128]
    __shared__ float cs[4][64];        // colsums: 0 e3, 1 new_e, 2 f3, 3 new_f
    __shared__ float msrc[4][64];      // colsums: 0 e1, 1 f1, 2 e2, 3 f2
    __shared__ float csk[2][128];      // 1^T k1 , 1^T k2
    __shared__ float sPd[128], sQd[128], sGd[128], sBd[128];
    __shared__ float a8[8];
    __shared__ float aScE[4], aScF[4];

    const int b = blockIdx.x;
    const int tid = threadIdx.x;
    const int lane = tid & 63;
    const int w = tid >> 6;
    const int l15 = lane & 15;
    const int lhi = lane >> 4;
    const f32x4 Z4 = {0.f, 0.f, 0.f, 0.f};

    // ---- zero LDS (EFt pads must be 0 for MFMA K-padding) ----
    {
        uint4 z; z.x = z.y = z.z = z.w = 0u;
        uint4* p = (uint4*)EFt;
        for (int i = tid; i < 128 * EFT_S * 2 / 16; i += 256) p[i] = z;
        ((float*)cs)[tid] = 0.0f;   // 4*64 == 256
    }
    if (tid < NB) {
        sPd[tid] = Pdg[b * NB + tid]; sQd[tid] = Qdg[b * NB + tid];
        sGd[tid] = Gdg[b * NB + tid]; sBd[tid] = Bdg[b * NB + tid];
    } else if (tid < 128) {
        sPd[tid] = 0.f; sQd[tid] = 0.f; sGd[tid] = 1.f; sBd[tid] = 1.f;
    }
    __syncthreads();

    // ---- stage e,f -> EFt (transpose + fp16) ----
    const float* eb = E + (size_t)b * NB * 64;
    const float* fb = F + (size_t)b * NB * 64;
    for (int ch = tid; ch < NB * 16; ch += 256) {
        int row = ch >> 4, dq = ch & 15;
        const float4 v = *(const float4*)(eb + row * 64 + dq * 4);
        const float4 u = *(const float4*)(fb + row * 64 + dq * 4);
        EFt[(dq * 4 + 0) * EFT_S + row] = (_Float16)v.x;
        EFt[(dq * 4 + 1) * EFT_S + row] = (_Float16)v.y;
        EFt[(dq * 4 + 2) * EFT_S + row] = (_Float16)v.z;
        EFt[(dq * 4 + 3) * EFT_S + row] = (_Float16)v.w;
        EFt[(64 + dq * 4 + 0) * EFT_S + row] = (_Float16)u.x;
        EFt[(64 + dq * 4 + 1) * EFT_S + row] = (_Float16)u.y;
        EFt[(64 + dq * 4 + 2) * EFT_S + row] = (_Float16)u.z;
        EFt[(64 + dq * 4 + 3) * EFT_S + row] = (_Float16)u.w;
    }
    __syncthreads();

    // ---- stage-1: G and B products ----
    f32x4 accG[2][8], accB[2][8];
#pragma unroll
    for (int rf = 0; rf < 2; rf++)
#pragma unroll
        for (int c = 0; c < 8; c++) { accG[rf][c] = Z4; accB[rf][c] = Z4; }
    stage1(Gn + (size_t)b * MSZ, EFt, w, lane, accG);
    stage1(Bn + (size_t)b * MSZ, EFt, w, lane, accB);

    // ---- elementwise physics (lane-local: d-col in frag c, f-col in frag c+4) ----
#pragma unroll
    for (int c = 0; c < 4; c++) {
        float se3 = 0, sf3 = 0, sne = 0, snf = 0;
#pragma unroll
        for (int rf = 0; rf < 2; rf++) {
#pragma unroll
            for (int r = 0; r < 4; r++) {
                int row = w * 32 + rf * 16 + lhi * 4 + r;
                int d = c * 16 + l15;
                float Ge = accG[rf][c][r], Gf = accG[rf][c + 4][r];
                float Be = accB[rf][c][r], Bf = accB[rf][c + 4][r];
                float ev = (float)EFt[d * EFT_S + row];
                float fv = (float)EFt[(64 + d) * EFT_S + row];
                float pd = sPd[row], qd = sQd[row], gd = sGd[row], bd = sBd[row];
                float ef2 = ev * ev + fv * fv;
                float ib = 1.0f / (ef2 + 0.1f);
                float alpha = (pd * ev + qd * fv) * ib - Ge - Bf;
                float beta  = (qd * ev - pd * fv) * ib + Gf + Bf;   // faithful: uses Bf
                float ibg = 1.0f / (gd * gd + bd * bd);
                float e3 = (alpha * gd + beta * bd) * ibg;
                float f3 = (beta * gd - alpha * bd) * ibg;
                float bs1 = Ge - Bf, bs2 = Gf + Be;
                float Pt = pd - ef2 * gd, Qt = qd + ef2 * bd;
                float ne = (Pt * bs1 + Qt * bs2) * ibg;
                float nf = (Pt * bs2 - Qt * bs1) * ibg;
                accG[rf][c][r] = e3; accG[rf][c + 4][r] = f3;
                accB[rf][c][r] = ne; accB[rf][c + 4][r] = nf;
                if (row < NB) { se3 += e3; sf3 += f3; sne += ne; snf += nf; }
            }
        }
        se3 += __shfl_xor(se3, 16); se3 += __shfl_xor(se3, 32);
        sf3 += __shfl_xor(sf3, 16); sf3 += __shfl_xor(sf3, 32);
        sne += __shfl_xor(sne, 16); sne += __shfl_xor(sne, 32);
        snf += __shfl_xor(snf, 16); snf += __shfl_xor(snf, 32);
        if (lhi == 0) {
            atomicAdd(&cs[0][c * 16 + l15], se3);
            atomicAdd(&cs[1][c * 16 + l15], sne);
            atomicAdd(&cs[2][c * 16 + l15], sf3);
            atomicAdd(&cs[3][c * 16 + l15], snf);
        }
    }
    __syncthreads();

    // ---- column sums of k1/k2 (linearity: mean(k@x) = (1^T k / N) @ x) ----
    if (tid < NB) {
        const float* p = K1 + (size_t)b * MSZ + tid;
        float s = 0;
        for (int r = 0; r < NB; r++) s += p[(size_t)r * NB];
        csk[0][tid] = s;
    } else if (tid < 128) csk[0][tid] = 0.f;
    else if (tid < 128 + NB) {
        const float* p = K2 + (size_t)b * MSZ + (tid - 128);
        float s = 0;
        for (int r = 0; r < NB; r++) s += p[(size_t)r * NB];
        csk[1][tid - 128] = s;
    } else csk[1][tid - 128] = 0.f;
    __syncthreads();

    // ---- mean vectors for e1,f1,e2,f2 ----
    {
        const float* ck = csk[w >> 1];
        int er = (w & 1) * 64 + lane;
        float s = 0;
        for (int n = 0; n < NB; n++) s += ck[n] * (float)EFt[er * EFT_S + n];
        msrc[w][lane] = s;
    }
    __syncthreads();

    // ---- attention scalars (wave w handles e-source w and f-source w) ----
    {
        const float* srcE = (w == 0) ? cs[0] : (w == 1) ? cs[1] : (w == 2) ? msrc[0] : msrc[2];
        const float* srcF = (w == 0) ? cs[2] : (w == 1) ? cs[3] : (w == 2) ? msrc[1] : msrc[3];
        float xe = srcE[lane] * wae[lane];
        float xf = srcF[lane] * waf[lane];
#pragma unroll
        for (int m = 1; m < 64; m <<= 1) { xe += __shfl_xor(xe, m); xf += __shfl_xor(xf, m); }
        if (lane == 0) {
            a8[w]     = 1.0f / (1.0f + __expf(-(xe * (1.0f / NB) + bae[0])));
            a8[w + 4] = 1.0f / (1.0f + __expf(-(xf * (1.0f / NB) + baf[0])));
        }
    }
    __syncthreads();
    if (tid == 0) {
        float ebs = a8[0] + a8[1] + a8[2] + a8[3] + 1e-4f;
        float fbs = a8[4] + a8[5] + a8[6] + a8[7] + 1e-4f;
#pragma unroll
        for (int j = 0; j < 4; j++) { aScE[j] = a8[j] / ebs; aScF[j] = a8[4 + j] / fbs; }
    }
    __syncthreads();

    // ---- stage-2: out = sum_j scale_j * X_j @ W_j  (5 K-blocks) ----
    f32x4 VE[2][4], VF[2][4];
#pragma unroll
    for (int rf = 0; rf < 2; rf++)
#pragma unroll
        for (int c = 0; c < 4; c++) { VE[rf][c] = Z4; VF[rf][c] = Z4; }

    writeRT(RT, accG, aScE[0], aScF[0], w, lane);   // e3 | f3
    __syncthreads();
    s2round(RT, W1P, W2P, 0, w, lane, VE, VF);
    __syncthreads();
    writeRT(RT, accB, aScE[1], aScF[1], w, lane);   // new_e | new_f
    __syncthreads();
    s2round(RT, W1P, W2P, 1, w, lane, VE, VF);
    __syncthreads();

    f32x4 accK[2][8];
#pragma unroll
    for (int rf = 0; rf < 2; rf++)
#pragma unroll
        for (int c = 0; c < 8; c++) accK[rf][c] = Z4;
    stage1(K1 + (size_t)b * MSZ, EFt, w, lane, accK);   // e1 | f1
    writeRT(RT, accK, aScE[2], aScF[2], w, lane);
    __syncthreads();
    s2round(RT, W1P, W2P, 2, w, lane, VE, VF);
    __syncthreads();

#pragma unroll
    for (int rf = 0; rf < 2; rf++)
#pragma unroll
        for (int c = 0; c < 8; c++) accK[rf][c] = Z4;
    stage1(K2 + (size_t)b * MSZ, EFt, w, lane, accK);   // e2 | f2
    writeRT(RT, accK, aScE[3], aScF[3], w, lane);
    __syncthreads();
    s2round(RT, W1P, W2P, 3, w, lane, VE, VF);

    // ---- round 4: + e @ W1[256:320], + f @ W2[256:320]  (A from EFt, unscaled) ----
#pragma unroll
    for (int th = 0; th < 2; th++) {
        int t = 8 + th;
        f16x8 ae[2], af[2];
#pragma unroll
        for (int rf = 0; rf < 2; rf++) {
            int row = w * 32 + rf * 16 + l15;
            int kk = th * 32 + lhi * 8;
            f16x8 ue, uf;
#pragma unroll
            for (int jj = 0; jj < 8; jj++) {
                ue[jj] = EFt[(kk + jj) * EFT_S + row];
                uf[jj] = EFt[(64 + kk + jj) * EFT_S + row];
            }
            ae[rf] = ue; af[rf] = uf;
        }
#pragma unroll
        for (int c = 0; c < 4; c++) {
            f16x8 bw1 = *(const f16x8*)&W1P[((t * 4 + c) * 64 + lane) * 8];
            f16x8 bw2 = *(const f16x8*)&W2P[((t * 4 + c) * 64 + lane) * 8];
#pragma unroll
            for (int rf = 0; rf < 2; rf++) {
                VE[rf][c] = mfma16(ae[rf], bw1, VE[rf][c]);
                VF[rf][c] = mfma16(af[rf], bw2, VF[rf][c]);
            }
        }
    }

    // ---- epilogue: bias + relu + store ----
#pragma unroll
    for (int c = 0; c < 4; c++) {
        float bb1 = b1[c * 16 + l15];
        float bb2 = b2[c * 16 + l15];
#pragma unroll
        for (int rf = 0; rf < 2; rf++) {
#pragma unroll
            for (int r = 0; r < 4; r++) {
                int row = w * 32 + rf * 16 + lhi * 4 + r;
                if (row < NB) {
                    size_t o = ((size_t)b * NB + row) * 64 + c * 16 + l15;
                    outE[o] = fmaxf(VE[rf][c][r] + bb1, 0.0f);
                    outF[o] = fmaxf(VF[rf][c][r] + bb2, 0.0f);
                }
            }
        }
    }
}

extern "C" void kernel_launch(void* const* d_in, const int* in_sizes, int n_in,
                              void* d_out, int out_size, void* d_ws, size_t ws_size,
                              hipStream_t stream)
{
    (void)in_sizes; (void)n_in; (void)out_size; (void)ws_size;
    const float* E   = (const float*)d_in[0];
    const float* F   = (const float*)d_in[1];
    const float* K1  = (const float*)d_in[2];
    const float* K2  = (const float*)d_in[3];
    const float* Gn  = (const float*)d_in[4];
    const float* Bn  = (const float*)d_in[5];
    const float* Gdg = (const float*)d_in[6];
    const float* Bdg = (const float*)d_in[7];
    const float* Pdg = (const float*)d_in[8];
    const float* Qdg = (const float*)d_in[9];
    const float* W1  = (const float*)d_in[10];
    const float* b1  = (const float*)d_in[11];
    const float* W2  = (const float*)d_in[12];
    const float* b2  = (const float*)d_in[13];
    const float* wae = (const float*)d_in[14];
    const float* bae = (const float*)d_in[15];
    const float* waf = (const float*)d_in[16];
    const float* baf = (const float*)d_in[17];

    _Float16* WP = (_Float16*)d_ws;           // 2 * 20480 fp16 = 80 KB
    float* outE = (float*)d_out;
    float* outF = outE + (size_t)2048 * NB * 64;

    prep_w<<<20, 256, 0, stream>>>(W1, W2, WP);
    gcn_main<<<2048, 256, 0, stream>>>(E, F, K1, K2, Gn, Bn, Gdg, Bdg, Pdg, Qdg,
                                       b1, b2, wae, bae, waf, baf,
                                       WP, WP + 20480, outE, outF);
}